// Round 7
// baseline (568.409 us; speedup 1.0000x reference)
//
#include <hip/hip_runtime.h>
#include <math.h>

#define NG 64
#define NM 256
#define ND 256
#define NK 16
#define NR (NG * NM)  // 16384 rows total
#define NB 16         // nodes per edge-MLP block

#define MASSF 0.9f

typedef __attribute__((ext_vector_type(8))) short bf16x8;
typedef __attribute__((ext_vector_type(4))) float f32x4;

static __device__ __forceinline__ short f2bf(float x) {
  union {
    float f;
    unsigned u;
  } v;
  v.f = x;
  unsigned r = v.u + 0x7FFFu + ((v.u >> 16) & 1u);
  return (short)(r >> 16);
}
static __device__ __forceinline__ float bf2f(short x) {
  union {
    unsigned u;
    float f;
  } v;
  v.u = ((unsigned)(unsigned short)x) << 16;
  return v.f;
}

// ---------------- prep: W2^T, W1cat = [W1hi - W1lo ; W1lo]^T, biascat ----------
__global__ __launch_bounds__(256) void prep_k(const float* __restrict__ W1,
                                              const float* __restrict__ b1,
                                              const float* __restrict__ W2,
                                              short* __restrict__ w2t, short* __restrict__ w1cat,
                                              float* __restrict__ biascat) {
  const int b = blockIdx.x, k = threadIdx.x;
  if (b < 256) {
    w2t[b * 256 + k] = f2bf(W2[(size_t)k * 256 + b]);
  } else {
    const int n = b - 256;  // 0..511
    float v;
    if (n < 256)
      v = W1[(size_t)k * 256 + n] - W1[(size_t)(k + 256) * 256 + n];
    else
      v = W1[(size_t)(k + 256) * 256 + (n - 256)];
    w1cat[(size_t)n * 256 + k] = f2bf(v);
    if (k == 0) biascat[n] = (n < 256) ? b1[n] : 0.f;
  }
}

// ---------------- encoder GEMM fp32: C = relu(A@B + bias), + bf16 copy --------
__global__ __launch_bounds__(256) void gemm_nn2_k(const float* __restrict__ A,
                                                  const float* __restrict__ B,
                                                  const float* __restrict__ bias,
                                                  float* __restrict__ C,
                                                  short* __restrict__ Cbf) {
  __shared__ float As[2][16][68];
  __shared__ float Bs[2][16][128];
  const int tid = threadIdx.x;
  const int tx = tid & 15, ty = tid >> 4;
  const int m0 = blockIdx.y * 64, n0 = blockIdx.x * 128;
  const int arow = tid >> 2, akc = (tid & 3) * 4;
  const int bkr = tid >> 4, bcc = (tid & 15) * 4;
  float4 av, bv0, bv1;
  float acc[4][8] = {};
  auto gload = [&](int k0) {
    av = *(const float4*)&A[(size_t)(m0 + arow) * 256 + k0 + akc];
    bv0 = *(const float4*)&B[(size_t)(k0 + bkr) * 256 + n0 + bcc];
    bv1 = *(const float4*)&B[(size_t)(k0 + bkr) * 256 + n0 + 64 + bcc];
  };
  auto swrite = [&](int buf) {
    As[buf][akc + 0][arow] = av.x;
    As[buf][akc + 1][arow] = av.y;
    As[buf][akc + 2][arow] = av.z;
    As[buf][akc + 3][arow] = av.w;
    *(float4*)&Bs[buf][bkr][bcc] = bv0;
    *(float4*)&Bs[buf][bkr][64 + bcc] = bv1;
  };
  gload(0);
  swrite(0);
  __syncthreads();
  for (int s = 0; s < 16; ++s) {
    if (s < 15) gload((s + 1) * 16);
    const int buf = s & 1;
#pragma unroll
    for (int kk = 0; kk < 16; ++kk) {
      const float4 a0 = *(const float4*)&As[buf][kk][ty * 4];
      const float4 b0 = *(const float4*)&Bs[buf][kk][tx * 4];
      const float4 b1 = *(const float4*)&Bs[buf][kk][64 + tx * 4];
      const float aa[4] = {a0.x, a0.y, a0.z, a0.w};
      const float bb[8] = {b0.x, b0.y, b0.z, b0.w, b1.x, b1.y, b1.z, b1.w};
#pragma unroll
      for (int i = 0; i < 4; ++i)
#pragma unroll
        for (int j = 0; j < 8; ++j) acc[i][j] = fmaf(aa[i], bb[j], acc[i][j]);
    }
    if (s < 15) swrite((s + 1) & 1);
    __syncthreads();
  }
  const float4 bia0 = *(const float4*)&bias[n0 + tx * 4];
  const float4 bia1 = *(const float4*)&bias[n0 + 64 + tx * 4];
#pragma unroll
  for (int i = 0; i < 4; ++i) {
    const size_t row = (size_t)(m0 + ty * 4 + i);
    float4 o0 = {fmaxf(acc[i][0] + bia0.x, 0.f), fmaxf(acc[i][1] + bia0.y, 0.f),
                 fmaxf(acc[i][2] + bia0.z, 0.f), fmaxf(acc[i][3] + bia0.w, 0.f)};
    float4 o1 = {fmaxf(acc[i][4] + bia1.x, 0.f), fmaxf(acc[i][5] + bia1.y, 0.f),
                 fmaxf(acc[i][6] + bia1.z, 0.f), fmaxf(acc[i][7] + bia1.w, 0.f)};
    *(float4*)&C[row * 256 + n0 + tx * 4] = o0;
    *(float4*)&C[row * 256 + n0 + 64 + tx * 4] = o1;
    short4 h0 = {f2bf(o0.x), f2bf(o0.y), f2bf(o0.z), f2bf(o0.w)};
    short4 h1 = {f2bf(o1.x), f2bf(o1.y), f2bf(o1.z), f2bf(o1.w)};
    *(short4*)&Cbf[row * 256 + n0 + tx * 4] = h0;
    *(short4*)&Cbf[row * 256 + n0 + 64 + tx * 4] = h1;
  }
}

// ---------------- symmetric gram NT fp32 per graph: S_g = h_g @ h_g^T --------
__global__ __launch_bounds__(256) void gemm_nt2_k(const float* __restrict__ h,
                                                  float* __restrict__ C) {
  const int bx = blockIdx.x, by = blockIdx.y, g = blockIdx.z;
  if (bx == 0 && by >= 2) return;  // covered by mirror of (bx=1, by<2)
  __shared__ float As[2][16][68];
  __shared__ float Bs[2][16][128];
  const float* Ag = h + (size_t)g * NM * ND;
  float* Cg = C + (size_t)g * NM * NM;
  const int tid = threadIdx.x;
  const int tx = tid & 15, ty = tid >> 4;
  const int m0 = by * 64, n0 = bx * 128;
  const int arow = tid >> 2, akc = (tid & 3) * 4;
  const int brow = tid >> 1, bkc = (tid & 1) * 8;
  float4 av, bva, bvb;
  float acc[4][8] = {};
  auto gload = [&](int k0) {
    av = *(const float4*)&Ag[(size_t)(m0 + arow) * 256 + k0 + akc];
    bva = *(const float4*)&Ag[(size_t)(n0 + brow) * 256 + k0 + bkc];
    bvb = *(const float4*)&Ag[(size_t)(n0 + brow) * 256 + k0 + bkc + 4];
  };
  auto swrite = [&](int buf) {
    As[buf][akc + 0][arow] = av.x;
    As[buf][akc + 1][arow] = av.y;
    As[buf][akc + 2][arow] = av.z;
    As[buf][akc + 3][arow] = av.w;
    Bs[buf][bkc + 0][brow] = bva.x;
    Bs[buf][bkc + 1][brow] = bva.y;
    Bs[buf][bkc + 2][brow] = bva.z;
    Bs[buf][bkc + 3][brow] = bva.w;
    Bs[buf][bkc + 4][brow] = bvb.x;
    Bs[buf][bkc + 5][brow] = bvb.y;
    Bs[buf][bkc + 6][brow] = bvb.z;
    Bs[buf][bkc + 7][brow] = bvb.w;
  };
  gload(0);
  swrite(0);
  __syncthreads();
  for (int s = 0; s < 16; ++s) {
    if (s < 15) gload((s + 1) * 16);
    const int buf = s & 1;
#pragma unroll
    for (int kk = 0; kk < 16; ++kk) {
      const float4 a0 = *(const float4*)&As[buf][kk][ty * 4];
      const float4 b0 = *(const float4*)&Bs[buf][kk][tx * 4];
      const float4 b1 = *(const float4*)&Bs[buf][kk][64 + tx * 4];
      const float aa[4] = {a0.x, a0.y, a0.z, a0.w};
      const float bb[8] = {b0.x, b0.y, b0.z, b0.w, b1.x, b1.y, b1.z, b1.w};
#pragma unroll
      for (int i = 0; i < 4; ++i)
#pragma unroll
        for (int j = 0; j < 8; ++j) acc[i][j] = fmaf(aa[i], bb[j], acc[i][j]);
    }
    if (s < 15) swrite((s + 1) & 1);
    __syncthreads();
  }
#pragma unroll
  for (int i = 0; i < 4; ++i) {
    const size_t row = (size_t)(m0 + ty * 4 + i);
    float4 o0 = {acc[i][0], acc[i][1], acc[i][2], acc[i][3]};
    float4 o1 = {acc[i][4], acc[i][5], acc[i][6], acc[i][7]};
    *(float4*)&Cg[row * 256 + n0 + tx * 4] = o0;
    *(float4*)&Cg[row * 256 + n0 + 64 + tx * 4] = o1;
  }
  if (bx == 1 && by < 2) {  // mirror into the skipped lower-left region
#pragma unroll
    for (int j = 0; j < 4; ++j) {
      const size_t col0 = (size_t)(n0 + tx * 4 + j);
      const size_t col1 = (size_t)(n0 + 64 + tx * 4 + j);
      float4 t0 = {acc[0][j], acc[1][j], acc[2][j], acc[3][j]};
      float4 t1 = {acc[0][4 + j], acc[1][4 + j], acc[2][4 + j], acc[3][4 + j]};
      *(float4*)&Cg[col0 * 256 + m0 + ty * 4] = t0;
      *(float4*)&Cg[col1 * 256 + m0 + ty * 4] = t1;
    }
  }
}

// ---------------- diagonal of S -> sq (row sum-of-squares) ----------------
__global__ __launch_bounds__(256) void diag_k(const float* __restrict__ S,
                                              float* __restrict__ sq) {
  const int g = blockIdx.x, m = threadIdx.x;
  sq[g * 256 + m] = S[(size_t)g * NM * NM + (size_t)m * 257];
}

// ---------------- MFMA GEMM: [16384,256]bf16 @ w1cat^T -> baseb, n1b (bf16) ---
__global__ __launch_bounds__(256, 2) void mlp1_mfma_k(const short* __restrict__ A,
                                                      const short* __restrict__ Bt,
                                                      const float* __restrict__ biascat,
                                                      short* __restrict__ baseb,
                                                      short* __restrict__ n1b) {
  __shared__ char As[64 * 512];
  const int tid = threadIdx.x;
  const int l = tid & 63, wv = tid >> 6;
  const int r = l & 15, gq = l >> 4;
  const int m0 = blockIdx.y * 64, n0 = blockIdx.x * 128;
  bf16x8 bfr[2][8];
  float bv[2];
#pragma unroll
  for (int nt = 0; nt < 2; ++nt) {
    const int col = n0 + wv * 32 + nt * 16 + r;
    const short* wb = Bt + (size_t)col * 256 + gq * 8;
#pragma unroll
    for (int ks = 0; ks < 8; ++ks) bfr[nt][ks] = *(const bf16x8*)(wb + ks * 32);
    bv[nt] = biascat[col];
  }
  const int row = tid >> 2, ch = tid & 3;
  const char* ag = (const char*)(A + (size_t)(m0 + row) * 256) + ch * 128;
  char* lb = As + row * 512;
#pragma unroll
  for (int j = 0; j < 8; ++j)
    *(bf16x8*)(lb + (((ch * 128 + j * 16)) ^ ((row & 7) << 4))) = *(const bf16x8*)(ag + j * 16);
  __syncthreads();
  f32x4 acc[4][2];
#pragma unroll
  for (int mt = 0; mt < 4; ++mt)
#pragma unroll
    for (int nt = 0; nt < 2; ++nt) acc[mt][nt] = (f32x4){0.f, 0.f, 0.f, 0.f};
#pragma unroll
  for (int ks = 0; ks < 8; ++ks) {
    bf16x8 a[4];
#pragma unroll
    for (int mt = 0; mt < 4; ++mt)
      a[mt] = *(const bf16x8*)(As + (mt * 16 + r) * 512 + ((gq * 16 + ks * 64) ^ ((r & 7) << 4)));
#pragma unroll
    for (int mt = 0; mt < 4; ++mt)
#pragma unroll
      for (int nt = 0; nt < 2; ++nt)
        acc[mt][nt] = __builtin_amdgcn_mfma_f32_16x16x32_bf16(a[mt], bfr[nt][ks], acc[mt][nt], 0, 0, 0);
  }
  short* dst = (n0 < 256) ? baseb : n1b;
  const int cb = (n0 < 256) ? n0 : n0 - 256;
#pragma unroll
  for (int mt = 0; mt < 4; ++mt)
#pragma unroll
    for (int nt = 0; nt < 2; ++nt) {
      const int col = cb + wv * 32 + nt * 16 + r;
#pragma unroll
      for (int reg = 0; reg < 4; ++reg) {
        const int rw = m0 + mt * 16 + gq * 4 + reg;
        dst[(size_t)rw * 256 + col] = f2bf(acc[mt][nt][reg] + bv[nt]);
      }
    }
}

// ---------------- MFMA cost GEMM -> P0 = exp(corr/(nA nB lam)), batched --------
__global__ __launch_bounds__(256, 2) void cost_mfma_k(const short* __restrict__ featT,
                                                      const short* __restrict__ featD,
                                                      const float* __restrict__ nA,
                                                      const float* __restrict__ nB,
                                                      const float* __restrict__ eps,
                                                      float* __restrict__ P) {
  __shared__ char As[64 * 512];
  const int g = blockIdx.z;
  const short* A = featT + (size_t)g * NM * ND;
  const short* Bt = featD + (size_t)g * NM * ND;
  const int tid = threadIdx.x;
  const int l = tid & 63, wv = tid >> 6;
  const int r = l & 15, gq = l >> 4;
  const int m0 = blockIdx.y * 64, n0 = blockIdx.x * 128;
  bf16x8 bfr[2][8];
  float rnb[2];
#pragma unroll
  for (int nt = 0; nt < 2; ++nt) {
    const int col = n0 + wv * 32 + nt * 16 + r;
    const short* wb = Bt + (size_t)col * 256 + gq * 8;
#pragma unroll
    for (int ks = 0; ks < 8; ++ks) bfr[nt][ks] = *(const bf16x8*)(wb + ks * 32);
    rnb[nt] = 1.0f / nB[g * NM + col];
  }
  const int row = tid >> 2, ch = tid & 3;
  const char* ag = (const char*)(A + (size_t)(m0 + row) * 256) + ch * 128;
  char* lb = As + row * 512;
#pragma unroll
  for (int j = 0; j < 8; ++j)
    *(bf16x8*)(lb + (((ch * 128 + j * 16)) ^ ((row & 7) << 4))) = *(const bf16x8*)(ag + j * 16);
  __syncthreads();
  f32x4 acc[4][2];
#pragma unroll
  for (int mt = 0; mt < 4; ++mt)
#pragma unroll
    for (int nt = 0; nt < 2; ++nt) acc[mt][nt] = (f32x4){0.f, 0.f, 0.f, 0.f};
#pragma unroll
  for (int ks = 0; ks < 8; ++ks) {
    bf16x8 a[4];
#pragma unroll
    for (int mt = 0; mt < 4; ++mt)
      a[mt] = *(const bf16x8*)(As + (mt * 16 + r) * 512 + ((gq * 16 + ks * 64) ^ ((r & 7) << 4)));
#pragma unroll
    for (int mt = 0; mt < 4; ++mt)
#pragma unroll
      for (int nt = 0; nt < 2; ++nt)
        acc[mt][nt] = __builtin_amdgcn_mfma_f32_16x16x32_bf16(a[mt], bfr[nt][ks], acc[mt][nt], 0, 0, 0);
  }
  const float inv_lam = 1.0f / (expf(eps[0]) + 0.03f);
#pragma unroll
  for (int mt = 0; mt < 4; ++mt) {
    float ria[4];
#pragma unroll
    for (int reg = 0; reg < 4; ++reg)
      ria[reg] = inv_lam / nA[g * NM + m0 + mt * 16 + gq * 4 + reg];
#pragma unroll
    for (int nt = 0; nt < 2; ++nt) {
      const int col = n0 + wv * 32 + nt * 16 + r;
#pragma unroll
      for (int reg = 0; reg < 4; ++reg) {
        const int rw = m0 + mt * 16 + gq * 4 + reg;
        P[(size_t)g * NM * NM + (size_t)rw * 256 + col] =
            expf(acc[mt][nt][reg] * ria[reg] * rnb[nt]);
      }
    }
  }
}

// ---------------- top-16 nearest neighbors (wave per row) ----------------
__global__ __launch_bounds__(256) void topk_k(const float* __restrict__ S,
                                              const float* __restrict__ sq,
                                              int* __restrict__ idx) {
  const int w = threadIdx.x >> 6, lane = threadIdx.x & 63;
  const int row = blockIdx.x * 4 + w;
  const int g = row >> 8, m = row & 255;
  const float* Srow = S + (size_t)row * NM;
  const float* sqg = sq + g * NM;
  const float sm = sqg[m];
  const float4 sv = *(const float4*)&Srow[lane * 4];
  const float4 qv = *(const float4*)&sqg[lane * 4];
  float cand[4] = {sm + qv.x - 2.f * sv.x, sm + qv.y - 2.f * sv.y, sm + qv.z - 2.f * sv.z,
                   sm + qv.w - 2.f * sv.w};
#pragma unroll
  for (int t = 0; t < 4; ++t)
    if (lane * 4 + t == m) cand[t] = 1e30f;
  for (int rnd = 0; rnd < NK; ++rnd) {
    float bvv = cand[0];
    int bi = lane * 4;
#pragma unroll
    for (int t = 1; t < 4; ++t)
      if (cand[t] < bvv) {
        bvv = cand[t];
        bi = lane * 4 + t;
      }
#pragma unroll
    for (int off = 1; off < 64; off <<= 1) {
      const float ov = __shfl_xor(bvv, off);
      const int oi = __shfl_xor(bi, off);
      if (ov < bvv || (ov == bvv && oi < bi)) {
        bvv = ov;
        bi = oi;
      }
    }
    if (lane == 0) idx[(size_t)row * NK + rnd] = bi;
    if ((bi >> 2) == lane) cand[bi & 3] = 1e30f;
  }
}

// ---------------- edge MLP v5: fragment-major E (conflict-free), fused norm ---
// 4 waves; wave owns 4 col-tiles (bfr in 128 VGPR). E slot s=ks*64+lane holds
// E[row=s&15][col=(s>>6)*32+((s>>4)&3)*8 ..+8]; write addr=tid*16 (sequential),
// read addr=ks*1024+l*16 (sequential) -> zero bank conflicts by construction.
__global__ __launch_bounds__(256, 3) void edgemlp_mfma5_k(
    const short* __restrict__ baseb, const short* __restrict__ n1b, const int* __restrict__ idx,
    const short* __restrict__ w2t, const float* __restrict__ b2, short* __restrict__ featbf,
    float* __restrict__ nrm) {
  __shared__ short E[2][2][512 * 8];  // [buf][node][slot*8] = 32 KB
  __shared__ int sidx[NB * NK];       // 1 KB
  __shared__ float normp[NB][4];
  const int tid = threadIdx.x;
  const int l = tid & 63, wv = tid >> 6;
  const int node0 = blockIdx.x * NB;
  const int g = node0 >> 8;
  const int r = l & 15, gq = l >> 4;
  sidx[tid] = idx[(size_t)node0 * NK + tid];
  // B fragments: wave owns col-tiles nb = wv*4 + t
  bf16x8 bfr[4][8];
  float b2v[4];
#pragma unroll
  for (int t = 0; t < 4; ++t) {
    const int nb = wv * 4 + t;
    const short* wb = w2t + (size_t)(nb * 16 + r) * 256 + gq * 8;
#pragma unroll
    for (int ks = 0; ks < 8; ++ks) bfr[t][ks] = *(const bf16x8*)(wb + ks * 32);
    b2v[t] = b2[nb * 16 + r];
  }
  __syncthreads();  // sidx visible
  // staging role: thread t owns slots t (cols c1) and t+256 (cols c1+128), row sr
  const int sr = tid & 15;
  const int c1 = ((tid >> 4) & 3) * 8 + (tid >> 6) * 32;
  bf16x8 nsa0, nsa1, nsb0, nsb1, ba0, ba1, bb0, bb1;
  auto sload = [&](int s) {
    const int na = s * 2;
    const short* pa = n1b + ((size_t)(g * NM + sidx[na * NK + sr])) * 256;
    const short* pb = n1b + ((size_t)(g * NM + sidx[(na + 1) * NK + sr])) * 256;
    nsa0 = *(const bf16x8*)(pa + c1);
    nsa1 = *(const bf16x8*)(pa + c1 + 128);
    nsb0 = *(const bf16x8*)(pb + c1);
    nsb1 = *(const bf16x8*)(pb + c1 + 128);
    const short* qa = baseb + (size_t)(node0 + na) * 256;
    const short* qb = baseb + (size_t)(node0 + na + 1) * 256;
    ba0 = *(const bf16x8*)(qa + c1);
    ba1 = *(const bf16x8*)(qa + c1 + 128);
    bb0 = *(const bf16x8*)(qb + c1);
    bb1 = *(const bf16x8*)(qb + c1 + 128);
  };
  auto swrite = [&](int s) {
    const int buf = s & 1;
    bf16x8 w0, w1, w2, w3;
#pragma unroll
    for (int q = 0; q < 8; ++q) {
      w0[q] = f2bf(fmaxf(bf2f(ba0[q]) + bf2f(nsa0[q]), 0.f));
      w1[q] = f2bf(fmaxf(bf2f(ba1[q]) + bf2f(nsa1[q]), 0.f));
      w2[q] = f2bf(fmaxf(bf2f(bb0[q]) + bf2f(nsb0[q]), 0.f));
      w3[q] = f2bf(fmaxf(bf2f(bb1[q]) + bf2f(nsb1[q]), 0.f));
    }
    *(bf16x8*)&E[buf][0][tid * 8] = w0;
    *(bf16x8*)&E[buf][0][(tid + 256) * 8] = w1;
    *(bf16x8*)&E[buf][1][tid * 8] = w2;
    *(bf16x8*)&E[buf][1][(tid + 256) * 8] = w3;
  };
  sload(0);
  swrite(0);
  __syncthreads();
  for (int s = 0; s < NB / 2; ++s) {
    if (s + 1 < NB / 2) sload(s + 1);
    const int buf = s & 1;
    const short* e0 = &E[buf][0][0];
    const short* e1 = &E[buf][1][0];
    f32x4 acc[2][4];
#pragma unroll
    for (int q = 0; q < 2; ++q)
#pragma unroll
      for (int t = 0; t < 4; ++t) acc[q][t] = (f32x4){0.f, 0.f, 0.f, 0.f};
#pragma unroll
    for (int ks = 0; ks < 8; ++ks) {
      const bf16x8 a0 = *(const bf16x8*)(e0 + ks * 512 + l * 8);
      const bf16x8 a1 = *(const bf16x8*)(e1 + ks * 512 + l * 8);
#pragma unroll
      for (int t = 0; t < 4; ++t) {
        acc[0][t] = __builtin_amdgcn_mfma_f32_16x16x32_bf16(a0, bfr[t][ks], acc[0][t], 0, 0, 0);
        acc[1][t] = __builtin_amdgcn_mfma_f32_16x16x32_bf16(a1, bfr[t][ks], acc[1][t], 0, 0, 0);
      }
    }
#pragma unroll
    for (int q = 0; q < 2; ++q) {
      const int nd = node0 + s * 2 + q;
      float ss = 0.f;
      short hv[4];
#pragma unroll
      for (int t = 0; t < 4; ++t) {
        float m1 = fmaxf(fmaxf(acc[q][t][0], acc[q][t][1]), fmaxf(acc[q][t][2], acc[q][t][3]));
        m1 = fmaxf(m1, __shfl_xor(m1, 16));
        m1 = fmaxf(m1, __shfl_xor(m1, 32));
        hv[t] = f2bf(m1 + b2v[t]);
        const float o = bf2f(hv[t]);
        ss += o * o;
      }
      if (gq == 0) {
#pragma unroll
        for (int t = 0; t < 4; ++t) featbf[((size_t)nd << 8) + (wv * 4 + t) * 16 + r] = hv[t];
      }
      ss += __shfl_xor(ss, 1);
      ss += __shfl_xor(ss, 2);
      ss += __shfl_xor(ss, 4);
      ss += __shfl_xor(ss, 8);
      if (l == 0) normp[s * 2 + q][wv] = ss;
    }
    if (s + 1 < NB / 2) swrite(s + 1);
    __syncthreads();
  }
  if (tid < NB) {
    float s = normp[tid][0] + normp[tid][1] + normp[tid][2] + normp[tid][3];
    nrm[node0 + tid] = sqrtf(s);
  }
}

// ---------------- fused Sinkhorn, plain domain: block per graph, P in regs ----
__global__ __launch_bounds__(1024) void sinkhorn_k(float* __restrict__ P) {
  __shared__ float red[16][256];
  __shared__ float scal[256];
  const int t = threadIdx.x;
  const int tc = t & 15;
  const int trw = t >> 4;
  const int wv = t >> 6, l = t & 63;
  float* Pg = P + (size_t)blockIdx.x * NM * NM;
  float p[4][16];
#pragma unroll
  for (int i = 0; i < 4; ++i)
#pragma unroll
    for (int q = 0; q < 4; ++q)
      *(f32x4*)&p[i][q * 4] = *(const f32x4*)&Pg[(size_t)(trw * 4 + i) * NM + tc * 16 + q * 4];

  auto rowpass = [&]() {
#pragma unroll
    for (int i = 0; i < 4; ++i) {
      float s = p[i][0];
#pragma unroll
      for (int j = 1; j < 16; ++j) s += p[i][j];
      s += __shfl_xor(s, 1);
      s += __shfl_xor(s, 2);
      s += __shfl_xor(s, 4);
      s += __shfl_xor(s, 8);
      const float sc = MASSF / s;
#pragma unroll
      for (int j = 0; j < 16; ++j) p[i][j] *= sc;
    }
  };
  auto colpass = [&]() {
    float tmp[16];
#pragma unroll
    for (int j = 0; j < 16; ++j) tmp[j] = ((p[0][j] + p[1][j]) + (p[2][j] + p[3][j]));
#pragma unroll
    for (int j = 0; j < 16; ++j) {
      tmp[j] += __shfl_xor(tmp[j], 16);
      tmp[j] += __shfl_xor(tmp[j], 32);
    }
    if (l < 16) {
#pragma unroll
      for (int q = 0; q < 4; ++q)
        *(f32x4*)&red[wv][l * 16 + q * 4] = *(const f32x4*)&tmp[q * 4];
    }
    __syncthreads();
    if (t < 256) {
      float s = red[0][t];
#pragma unroll
      for (int w = 1; w < 16; ++w) s += red[w][t];
      scal[t] = MASSF / s;
    }
    __syncthreads();
#pragma unroll
    for (int j = 0; j < 16; ++j) {
      const float sc = scal[tc * 16 + j];
#pragma unroll
      for (int i = 0; i < 4; ++i) p[i][j] *= sc;
    }
    __syncthreads();
  };
  for (int it = 0; it < 7; ++it) {
    rowpass();
    colpass();
  }
  rowpass();
#pragma unroll
  for (int i = 0; i < 4; ++i)
#pragma unroll
    for (int q = 0; q < 4; ++q)
      *(f32x4*)&Pg[(size_t)(trw * 4 + i) * NM + tc * 16 + q * 4] = *(const f32x4*)&p[i][q * 4];
}

extern "C" void kernel_launch(void* const* d_in, const int* in_sizes, int n_in, void* d_out,
                              int out_size, void* d_ws, size_t ws_size, hipStream_t stream) {
  const float* tra_x = (const float*)d_in[0];
  const float* det_x = (const float*)d_in[1];
  const float* W_enc = (const float*)d_in[2];
  const float* b_enc = (const float*)d_in[3];
  const float* W1 = (const float*)d_in[4];
  const float* b1 = (const float*)d_in[5];
  const float* W2 = (const float*)d_in[6];
  const float* b2 = (const float*)d_in[7];
  const float* eps = (const float*)d_in[8];
  float* out = (float*)d_out;

  const size_t SZ = (size_t)NR * ND;
  float* h = (float*)d_ws;
  short* hbf = (short*)(h + SZ);
  short* baseb = hbf + SZ;
  short* n1b = baseb + SZ;
  short* featT = n1b + SZ;
  short* featD = featT + SZ;
  float* sq = (float*)(featD + SZ);
  float* nT = sq + NR;
  float* nD = nT + NR;
  int* idx = (int*)(nD + NR);
  short* w2t = (short*)(idx + (size_t)NR * NK);
  short* w1cat = w2t + 256 * 256;
  float* biascat = (float*)(w1cat + 512 * 256);
  float* S = out;  // gram scratch lives in d_out until cost overwrites it

  const float* xs[2] = {tra_x, det_x};
  short* feats[2] = {featT, featD};
  float* nrms[2] = {nT, nD};

  prep_k<<<768, 256, 0, stream>>>(W1, b1, W2, w2t, w1cat, biascat);
  for (int s2 = 0; s2 < 2; ++s2) {
    gemm_nn2_k<<<dim3(2, 256), 256, 0, stream>>>(xs[s2], W_enc, b_enc, h, hbf);
    mlp1_mfma_k<<<dim3(4, 256), 256, 0, stream>>>(hbf, w1cat, biascat, baseb, n1b);
    gemm_nt2_k<<<dim3(2, 4, NG), 256, 0, stream>>>(h, S);
    diag_k<<<NG, 256, 0, stream>>>(S, sq);
    topk_k<<<4096, 256, 0, stream>>>(S, sq, idx);
    edgemlp_mfma5_k<<<NR / NB, 256, 0, stream>>>(baseb, n1b, idx, w2t, b2, feats[s2], nrms[s2]);
  }
  cost_mfma_k<<<dim3(2, 4, NG), 256, 0, stream>>>(featT, featD, nT, nD, eps, out);
  sinkhorn_k<<<NG, 1024, 0, stream>>>(out);
}

// Round 8
// 399.543 us; speedup vs baseline: 1.4226x; 1.4226x over previous
//
#include <hip/hip_runtime.h>
#include <math.h>

#define NG 64
#define NM 256
#define ND 256
#define NK 16
#define NR (NG * NM)  // 16384 rows total
#define NB 16         // nodes per edge-MLP block

#define MASSF 0.9f

typedef __attribute__((ext_vector_type(8))) short bf16x8;
typedef __attribute__((ext_vector_type(4))) float f32x4;

static __device__ __forceinline__ short f2bf(float x) {
  union {
    float f;
    unsigned u;
  } v;
  v.f = x;
  unsigned r = v.u + 0x7FFFu + ((v.u >> 16) & 1u);
  return (short)(r >> 16);
}
static __device__ __forceinline__ float bf2f(short x) {
  union {
    unsigned u;
    float f;
  } v;
  v.u = ((unsigned)(unsigned short)x) << 16;
  return v.f;
}

// ---------------- prep: W2^T, W1cat = [W1hi - W1lo ; W1lo]^T, biascat ----------
__global__ __launch_bounds__(256) void prep_k(const float* __restrict__ W1,
                                              const float* __restrict__ b1,
                                              const float* __restrict__ W2,
                                              short* __restrict__ w2t, short* __restrict__ w1cat,
                                              float* __restrict__ biascat) {
  const int b = blockIdx.x, k = threadIdx.x;
  if (b < 256) {
    w2t[b * 256 + k] = f2bf(W2[(size_t)k * 256 + b]);
  } else {
    const int n = b - 256;  // 0..511
    float v;
    if (n < 256)
      v = W1[(size_t)k * 256 + n] - W1[(size_t)(k + 256) * 256 + n];
    else
      v = W1[(size_t)(k + 256) * 256 + (n - 256)];
    w1cat[(size_t)n * 256 + k] = f2bf(v);
    if (k == 0) biascat[n] = (n < 256) ? b1[n] : 0.f;
  }
}

// ---------------- encoder GEMM fp32: C = relu(A@B + bias), + bf16 copy --------
__global__ __launch_bounds__(256) void gemm_nn2_k(const float* __restrict__ A,
                                                  const float* __restrict__ B,
                                                  const float* __restrict__ bias,
                                                  float* __restrict__ C,
                                                  short* __restrict__ Cbf) {
  __shared__ float As[2][16][68];
  __shared__ float Bs[2][16][128];
  const int tid = threadIdx.x;
  const int tx = tid & 15, ty = tid >> 4;
  const int m0 = blockIdx.y * 64, n0 = blockIdx.x * 128;
  const int arow = tid >> 2, akc = (tid & 3) * 4;
  const int bkr = tid >> 4, bcc = (tid & 15) * 4;
  float4 av, bv0, bv1;
  float acc[4][8] = {};
  auto gload = [&](int k0) {
    av = *(const float4*)&A[(size_t)(m0 + arow) * 256 + k0 + akc];
    bv0 = *(const float4*)&B[(size_t)(k0 + bkr) * 256 + n0 + bcc];
    bv1 = *(const float4*)&B[(size_t)(k0 + bkr) * 256 + n0 + 64 + bcc];
  };
  auto swrite = [&](int buf) {
    As[buf][akc + 0][arow] = av.x;
    As[buf][akc + 1][arow] = av.y;
    As[buf][akc + 2][arow] = av.z;
    As[buf][akc + 3][arow] = av.w;
    *(float4*)&Bs[buf][bkr][bcc] = bv0;
    *(float4*)&Bs[buf][bkr][64 + bcc] = bv1;
  };
  gload(0);
  swrite(0);
  __syncthreads();
  for (int s = 0; s < 16; ++s) {
    if (s < 15) gload((s + 1) * 16);
    const int buf = s & 1;
#pragma unroll
    for (int kk = 0; kk < 16; ++kk) {
      const float4 a0 = *(const float4*)&As[buf][kk][ty * 4];
      const float4 b0 = *(const float4*)&Bs[buf][kk][tx * 4];
      const float4 b1 = *(const float4*)&Bs[buf][kk][64 + tx * 4];
      const float aa[4] = {a0.x, a0.y, a0.z, a0.w};
      const float bb[8] = {b0.x, b0.y, b0.z, b0.w, b1.x, b1.y, b1.z, b1.w};
#pragma unroll
      for (int i = 0; i < 4; ++i)
#pragma unroll
        for (int j = 0; j < 8; ++j) acc[i][j] = fmaf(aa[i], bb[j], acc[i][j]);
    }
    if (s < 15) swrite((s + 1) & 1);
    __syncthreads();
  }
  const float4 bia0 = *(const float4*)&bias[n0 + tx * 4];
  const float4 bia1 = *(const float4*)&bias[n0 + 64 + tx * 4];
#pragma unroll
  for (int i = 0; i < 4; ++i) {
    const size_t row = (size_t)(m0 + ty * 4 + i);
    float4 o0 = {fmaxf(acc[i][0] + bia0.x, 0.f), fmaxf(acc[i][1] + bia0.y, 0.f),
                 fmaxf(acc[i][2] + bia0.z, 0.f), fmaxf(acc[i][3] + bia0.w, 0.f)};
    float4 o1 = {fmaxf(acc[i][4] + bia1.x, 0.f), fmaxf(acc[i][5] + bia1.y, 0.f),
                 fmaxf(acc[i][6] + bia1.z, 0.f), fmaxf(acc[i][7] + bia1.w, 0.f)};
    *(float4*)&C[row * 256 + n0 + tx * 4] = o0;
    *(float4*)&C[row * 256 + n0 + 64 + tx * 4] = o1;
    short4 h0 = {f2bf(o0.x), f2bf(o0.y), f2bf(o0.z), f2bf(o0.w)};
    short4 h1 = {f2bf(o1.x), f2bf(o1.y), f2bf(o1.z), f2bf(o1.w)};
    *(short4*)&Cbf[row * 256 + n0 + tx * 4] = h0;
    *(short4*)&Cbf[row * 256 + n0 + 64 + tx * 4] = h1;
  }
}

// ---------------- symmetric gram NT fp32 per graph: S_g = h_g @ h_g^T --------
// XCD-swizzled flat index: each XCD owns 8 whole graphs (L2 locality).
__global__ __launch_bounds__(256) void gemm_nt2_k(const float* __restrict__ h,
                                                  float* __restrict__ C) {
  const int flat0 = blockIdx.x + 2 * (blockIdx.y + 4 * blockIdx.z);
  const int flat = ((flat0 & 7) << 6) | (flat0 >> 3);  // 512 blocks: %8 *64 + /8
  const int bx = flat & 1, by = (flat >> 1) & 3, g = flat >> 3;
  if (bx == 0 && by >= 2) return;  // covered by mirror of (bx=1, by<2)
  __shared__ float As[2][16][68];
  __shared__ float Bs[2][16][128];
  const float* Ag = h + (size_t)g * NM * ND;
  float* Cg = C + (size_t)g * NM * NM;
  const int tid = threadIdx.x;
  const int tx = tid & 15, ty = tid >> 4;
  const int m0 = by * 64, n0 = bx * 128;
  const int arow = tid >> 2, akc = (tid & 3) * 4;
  const int brow = tid >> 1, bkc = (tid & 1) * 8;
  float4 av, bva, bvb;
  float acc[4][8] = {};
  auto gload = [&](int k0) {
    av = *(const float4*)&Ag[(size_t)(m0 + arow) * 256 + k0 + akc];
    bva = *(const float4*)&Ag[(size_t)(n0 + brow) * 256 + k0 + bkc];
    bvb = *(const float4*)&Ag[(size_t)(n0 + brow) * 256 + k0 + bkc + 4];
  };
  auto swrite = [&](int buf) {
    As[buf][akc + 0][arow] = av.x;
    As[buf][akc + 1][arow] = av.y;
    As[buf][akc + 2][arow] = av.z;
    As[buf][akc + 3][arow] = av.w;
    Bs[buf][bkc + 0][brow] = bva.x;
    Bs[buf][bkc + 1][brow] = bva.y;
    Bs[buf][bkc + 2][brow] = bva.z;
    Bs[buf][bkc + 3][brow] = bva.w;
    Bs[buf][bkc + 4][brow] = bvb.x;
    Bs[buf][bkc + 5][brow] = bvb.y;
    Bs[buf][bkc + 6][brow] = bvb.z;
    Bs[buf][bkc + 7][brow] = bvb.w;
  };
  gload(0);
  swrite(0);
  __syncthreads();
  for (int s = 0; s < 16; ++s) {
    if (s < 15) gload((s + 1) * 16);
    const int buf = s & 1;
#pragma unroll
    for (int kk = 0; kk < 16; ++kk) {
      const float4 a0 = *(const float4*)&As[buf][kk][ty * 4];
      const float4 b0 = *(const float4*)&Bs[buf][kk][tx * 4];
      const float4 b1 = *(const float4*)&Bs[buf][kk][64 + tx * 4];
      const float aa[4] = {a0.x, a0.y, a0.z, a0.w};
      const float bb[8] = {b0.x, b0.y, b0.z, b0.w, b1.x, b1.y, b1.z, b1.w};
#pragma unroll
      for (int i = 0; i < 4; ++i)
#pragma unroll
        for (int j = 0; j < 8; ++j) acc[i][j] = fmaf(aa[i], bb[j], acc[i][j]);
    }
    if (s < 15) swrite((s + 1) & 1);
    __syncthreads();
  }
#pragma unroll
  for (int i = 0; i < 4; ++i) {
    const size_t row = (size_t)(m0 + ty * 4 + i);
    float4 o0 = {acc[i][0], acc[i][1], acc[i][2], acc[i][3]};
    float4 o1 = {acc[i][4], acc[i][5], acc[i][6], acc[i][7]};
    *(float4*)&Cg[row * 256 + n0 + tx * 4] = o0;
    *(float4*)&Cg[row * 256 + n0 + 64 + tx * 4] = o1;
  }
  if (bx == 1 && by < 2) {  // mirror into the skipped lower-left region
#pragma unroll
    for (int j = 0; j < 4; ++j) {
      const size_t col0 = (size_t)(n0 + tx * 4 + j);
      const size_t col1 = (size_t)(n0 + 64 + tx * 4 + j);
      float4 t0 = {acc[0][j], acc[1][j], acc[2][j], acc[3][j]};
      float4 t1 = {acc[0][4 + j], acc[1][4 + j], acc[2][4 + j], acc[3][4 + j]};
      *(float4*)&Cg[col0 * 256 + m0 + ty * 4] = t0;
      *(float4*)&Cg[col1 * 256 + m0 + ty * 4] = t1;
    }
  }
}

// ---------------- diagonal of S -> sq (row sum-of-squares) ----------------
__global__ __launch_bounds__(256) void diag_k(const float* __restrict__ S,
                                              float* __restrict__ sq) {
  const int g = blockIdx.x, m = threadIdx.x;
  sq[g * 256 + m] = S[(size_t)g * NM * NM + (size_t)m * 257];
}

// ---------------- MFMA GEMM: [16384,256]bf16 @ w1cat^T -> baseb, n1b (bf16) ---
__global__ __launch_bounds__(256, 2) void mlp1_mfma_k(const short* __restrict__ A,
                                                      const short* __restrict__ Bt,
                                                      const float* __restrict__ biascat,
                                                      short* __restrict__ baseb,
                                                      short* __restrict__ n1b) {
  __shared__ char As[64 * 512];
  const int tid = threadIdx.x;
  const int l = tid & 63, wv = tid >> 6;
  const int r = l & 15, gq = l >> 4;
  const int m0 = blockIdx.y * 64, n0 = blockIdx.x * 128;
  bf16x8 bfr[2][8];
  float bv[2];
#pragma unroll
  for (int nt = 0; nt < 2; ++nt) {
    const int col = n0 + wv * 32 + nt * 16 + r;
    const short* wb = Bt + (size_t)col * 256 + gq * 8;
#pragma unroll
    for (int ks = 0; ks < 8; ++ks) bfr[nt][ks] = *(const bf16x8*)(wb + ks * 32);
    bv[nt] = biascat[col];
  }
  const int row = tid >> 2, ch = tid & 3;
  const char* ag = (const char*)(A + (size_t)(m0 + row) * 256) + ch * 128;
  char* lb = As + row * 512;
#pragma unroll
  for (int j = 0; j < 8; ++j)
    *(bf16x8*)(lb + (((ch * 128 + j * 16)) ^ ((row & 7) << 4))) = *(const bf16x8*)(ag + j * 16);
  __syncthreads();
  f32x4 acc[4][2];
#pragma unroll
  for (int mt = 0; mt < 4; ++mt)
#pragma unroll
    for (int nt = 0; nt < 2; ++nt) acc[mt][nt] = (f32x4){0.f, 0.f, 0.f, 0.f};
#pragma unroll
  for (int ks = 0; ks < 8; ++ks) {
    bf16x8 a[4];
#pragma unroll
    for (int mt = 0; mt < 4; ++mt)
      a[mt] = *(const bf16x8*)(As + (mt * 16 + r) * 512 + ((gq * 16 + ks * 64) ^ ((r & 7) << 4)));
#pragma unroll
    for (int mt = 0; mt < 4; ++mt)
#pragma unroll
      for (int nt = 0; nt < 2; ++nt)
        acc[mt][nt] = __builtin_amdgcn_mfma_f32_16x16x32_bf16(a[mt], bfr[nt][ks], acc[mt][nt], 0, 0, 0);
  }
  short* dst = (n0 < 256) ? baseb : n1b;
  const int cb = (n0 < 256) ? n0 : n0 - 256;
#pragma unroll
  for (int mt = 0; mt < 4; ++mt)
#pragma unroll
    for (int nt = 0; nt < 2; ++nt) {
      const int col = cb + wv * 32 + nt * 16 + r;
#pragma unroll
      for (int reg = 0; reg < 4; ++reg) {
        const int rw = m0 + mt * 16 + gq * 4 + reg;
        dst[(size_t)rw * 256 + col] = f2bf(acc[mt][nt][reg] + bv[nt]);
      }
    }
}

// ---------------- MFMA cost GEMM -> P0 = exp(corr/(nA nB lam)), batched --------
__global__ __launch_bounds__(256, 2) void cost_mfma_k(const short* __restrict__ featT,
                                                      const short* __restrict__ featD,
                                                      const float* __restrict__ nA,
                                                      const float* __restrict__ nB,
                                                      const float* __restrict__ eps,
                                                      float* __restrict__ P) {
  __shared__ char As[64 * 512];
  const int g = blockIdx.z;
  const short* A = featT + (size_t)g * NM * ND;
  const short* Bt = featD + (size_t)g * NM * ND;
  const int tid = threadIdx.x;
  const int l = tid & 63, wv = tid >> 6;
  const int r = l & 15, gq = l >> 4;
  const int m0 = blockIdx.y * 64, n0 = blockIdx.x * 128;
  bf16x8 bfr[2][8];
  float rnb[2];
#pragma unroll
  for (int nt = 0; nt < 2; ++nt) {
    const int col = n0 + wv * 32 + nt * 16 + r;
    const short* wb = Bt + (size_t)col * 256 + gq * 8;
#pragma unroll
    for (int ks = 0; ks < 8; ++ks) bfr[nt][ks] = *(const bf16x8*)(wb + ks * 32);
    rnb[nt] = 1.0f / nB[g * NM + col];
  }
  const int row = tid >> 2, ch = tid & 3;
  const char* ag = (const char*)(A + (size_t)(m0 + row) * 256) + ch * 128;
  char* lb = As + row * 512;
#pragma unroll
  for (int j = 0; j < 8; ++j)
    *(bf16x8*)(lb + (((ch * 128 + j * 16)) ^ ((row & 7) << 4))) = *(const bf16x8*)(ag + j * 16);
  __syncthreads();
  f32x4 acc[4][2];
#pragma unroll
  for (int mt = 0; mt < 4; ++mt)
#pragma unroll
    for (int nt = 0; nt < 2; ++nt) acc[mt][nt] = (f32x4){0.f, 0.f, 0.f, 0.f};
#pragma unroll
  for (int ks = 0; ks < 8; ++ks) {
    bf16x8 a[4];
#pragma unroll
    for (int mt = 0; mt < 4; ++mt)
      a[mt] = *(const bf16x8*)(As + (mt * 16 + r) * 512 + ((gq * 16 + ks * 64) ^ ((r & 7) << 4)));
#pragma unroll
    for (int mt = 0; mt < 4; ++mt)
#pragma unroll
      for (int nt = 0; nt < 2; ++nt)
        acc[mt][nt] = __builtin_amdgcn_mfma_f32_16x16x32_bf16(a[mt], bfr[nt][ks], acc[mt][nt], 0, 0, 0);
  }
  const float inv_lam = 1.0f / (expf(eps[0]) + 0.03f);
#pragma unroll
  for (int mt = 0; mt < 4; ++mt) {
    float ria[4];
#pragma unroll
    for (int reg = 0; reg < 4; ++reg)
      ria[reg] = inv_lam / nA[g * NM + m0 + mt * 16 + gq * 4 + reg];
#pragma unroll
    for (int nt = 0; nt < 2; ++nt) {
      const int col = n0 + wv * 32 + nt * 16 + r;
#pragma unroll
      for (int reg = 0; reg < 4; ++reg) {
        const int rw = m0 + mt * 16 + gq * 4 + reg;
        P[(size_t)g * NM * NM + (size_t)rw * 256 + col] =
            expf(acc[mt][nt][reg] * ria[reg] * rnb[nt]);
      }
    }
  }
}

// ---------------- per-row L2 norm of bf16 feat ----------------
__global__ __launch_bounds__(256) void normrow_bf_k(const short* __restrict__ feat,
                                                    float* __restrict__ nrm) {
  const int w = threadIdx.x >> 6, lane = threadIdx.x & 63;
  const int row = blockIdx.x * 4 + w;
  const short4 v = *(const short4*)&feat[(size_t)row * ND + lane * 4];
  const float a = bf2f(v.x), b = bf2f(v.y), c = bf2f(v.z), d = bf2f(v.w);
  float s = a * a + b * b + c * c + d * d;
#pragma unroll
  for (int off = 32; off; off >>= 1) s += __shfl_xor(s, off);
  if (lane == 0) nrm[row] = sqrtf(s);
}

// ---------------- top-16 nearest neighbors (wave per row) ----------------
__global__ __launch_bounds__(256) void topk_k(const float* __restrict__ S,
                                              const float* __restrict__ sq,
                                              int* __restrict__ idx) {
  const int w = threadIdx.x >> 6, lane = threadIdx.x & 63;
  const int row = blockIdx.x * 4 + w;
  const int g = row >> 8, m = row & 255;
  const float* Srow = S + (size_t)row * NM;
  const float* sqg = sq + g * NM;
  const float sm = sqg[m];
  const float4 sv = *(const float4*)&Srow[lane * 4];
  const float4 qv = *(const float4*)&sqg[lane * 4];
  float cand[4] = {sm + qv.x - 2.f * sv.x, sm + qv.y - 2.f * sv.y, sm + qv.z - 2.f * sv.z,
                   sm + qv.w - 2.f * sv.w};
#pragma unroll
  for (int t = 0; t < 4; ++t)
    if (lane * 4 + t == m) cand[t] = 1e30f;
  for (int rnd = 0; rnd < NK; ++rnd) {
    float bvv = cand[0];
    int bi = lane * 4;
#pragma unroll
    for (int t = 1; t < 4; ++t)
      if (cand[t] < bvv) {
        bvv = cand[t];
        bi = lane * 4 + t;
      }
#pragma unroll
    for (int off = 1; off < 64; off <<= 1) {
      const float ov = __shfl_xor(bvv, off);
      const int oi = __shfl_xor(bi, off);
      if (ov < bvv || (ov == bvv && oi < bi)) {
        bvv = ov;
        bi = oi;
      }
    }
    if (lane == 0) idx[(size_t)row * NK + rnd] = bi;
    if ((bi >> 2) == lane) cand[bi & 3] = 1e30f;
  }
}

// ---------------- edge MLP via MFMA v6: v4 structure, NB=16, XCD swizzle ------
__global__ __launch_bounds__(512, 4) void edgemlp_mfma6_k(
    const short* __restrict__ baseb, const short* __restrict__ n1b, const int* __restrict__ idx,
    const short* __restrict__ w2t, const float* __restrict__ b2, short* __restrict__ featbf) {
  __shared__ short E[2][32 * 256];  // 2 x 16 KB, XOR-swizzled rows
  __shared__ int sidx[NB * NK];     // 256 ints
  const int tid = threadIdx.x;
  const int l = tid & 63, wv = tid >> 6;
  // XCD swizzle: 1024 blocks, %8 -> *128; each XCD gets 128 consecutive blocks
  // = 8 whole graphs -> n1b panels stay L2-resident.
  const int blk = ((blockIdx.x & 7) << 7) | (blockIdx.x >> 3);
  const int node0 = blk * NB;
  const int g = node0 >> 8;
  const int r = l & 15, gq = l >> 4;
  if (tid < NB * NK) sidx[tid] = idx[(size_t)node0 * NK + tid];
  bf16x8 bfr[2][8];
  float b2v[2];
#pragma unroll
  for (int t = 0; t < 2; ++t) {
    const int nb = wv * 2 + t;
    const short* wb = w2t + (size_t)(nb * 16 + r) * 256 + gq * 8;
#pragma unroll
    for (int ks = 0; ks < 8; ++ks) bfr[t][ks] = *(const bf16x8*)(wb + ks * 32);
    b2v[t] = b2[nb * 16 + r];
  }
  __syncthreads();  // sidx visible
  const int j = tid >> 5;        // row within node 0..15
  const int c = (tid & 31) * 8;  // col
  const unsigned wboff = (unsigned)((c * 2) ^ ((j & 7) << 4));
  bf16x8 ns0, ns1;
  auto sload = [&](int s) {  // issue n1 gathers for stage s (2 nodes)
    const int nb0 = s * 2;
    ns0 = *(const bf16x8*)(n1b + ((((size_t)g << 8) + sidx[nb0 * NK + j]) << 8) + c);
    ns1 = *(const bf16x8*)(n1b + ((((size_t)g << 8) + sidx[(nb0 + 1) * NK + j]) << 8) + c);
  };
  auto swrite = [&](int s) {  // relu(base+n1) -> bf16 swizzled LDS
    char* eb = (char*)&E[s & 1][0];
    const int nb0 = s * 2;
    const bf16x8 b0 = *(const bf16x8*)(baseb + (((size_t)(node0 + nb0)) << 8) + c);
    const bf16x8 b1 = *(const bf16x8*)(baseb + (((size_t)(node0 + nb0 + 1)) << 8) + c);
    bf16x8 w0, w1;
#pragma unroll
    for (int q = 0; q < 8; ++q) {
      w0[q] = f2bf(fmaxf(bf2f(b0[q]) + bf2f(ns0[q]), 0.f));
      w1[q] = f2bf(fmaxf(bf2f(b1[q]) + bf2f(ns1[q]), 0.f));
    }
    *(bf16x8*)(eb + (size_t)j * 512 + wboff) = w0;
    *(bf16x8*)(eb + (size_t)(16 + j) * 512 + wboff) = w1;
  };
  sload(0);
  swrite(0);
  __syncthreads();
  for (int s = 0; s < NB / 2; ++s) {
    if (s + 1 < NB / 2) sload(s + 1);
    const char* eb = (const char*)&E[s & 1][0];
#pragma unroll
    for (int q = 0; q < 2; ++q) {
      f32x4 acc0 = (f32x4){0.f, 0.f, 0.f, 0.f};
      f32x4 acc1 = (f32x4){0.f, 0.f, 0.f, 0.f};
      const int rowb = (q * 16 + r) * 512;
#pragma unroll
      for (int ks = 0; ks < 8; ++ks) {
        const bf16x8 a = *(const bf16x8*)(eb + rowb + ((gq * 16 + ks * 64) ^ ((r & 7) << 4)));
        acc0 = __builtin_amdgcn_mfma_f32_16x16x32_bf16(a, bfr[0][ks], acc0, 0, 0, 0);
        acc1 = __builtin_amdgcn_mfma_f32_16x16x32_bf16(a, bfr[1][ks], acc1, 0, 0, 0);
      }
      const int nd = node0 + s * 2 + q;
      float m0v = fmaxf(fmaxf(acc0[0], acc0[1]), fmaxf(acc0[2], acc0[3]));
      m0v = fmaxf(m0v, __shfl_xor(m0v, 16));
      m0v = fmaxf(m0v, __shfl_xor(m0v, 32));
      float m1v = fmaxf(fmaxf(acc1[0], acc1[1]), fmaxf(acc1[2], acc1[3]));
      m1v = fmaxf(m1v, __shfl_xor(m1v, 16));
      m1v = fmaxf(m1v, __shfl_xor(m1v, 32));
      if (gq == 0) {
        featbf[((size_t)nd << 8) + (wv * 2 + 0) * 16 + r] = f2bf(m0v + b2v[0]);
        featbf[((size_t)nd << 8) + (wv * 2 + 1) * 16 + r] = f2bf(m1v + b2v[1]);
      }
    }
    if (s + 1 < NB / 2) swrite(s + 1);
    __syncthreads();
  }
}

// ---------------- fused Sinkhorn, plain domain: block per graph, P in regs ----
__global__ __launch_bounds__(1024) void sinkhorn_k(float* __restrict__ P) {
  __shared__ float red[16][256];
  __shared__ float scal[256];
  const int t = threadIdx.x;
  const int tc = t & 15;
  const int trw = t >> 4;
  const int wv = t >> 6, l = t & 63;
  float* Pg = P + (size_t)blockIdx.x * NM * NM;
  float p[4][16];
#pragma unroll
  for (int i = 0; i < 4; ++i)
#pragma unroll
    for (int q = 0; q < 4; ++q)
      *(f32x4*)&p[i][q * 4] = *(const f32x4*)&Pg[(size_t)(trw * 4 + i) * NM + tc * 16 + q * 4];

  auto rowpass = [&]() {
#pragma unroll
    for (int i = 0; i < 4; ++i) {
      float s = p[i][0];
#pragma unroll
      for (int j = 1; j < 16; ++j) s += p[i][j];
      s += __shfl_xor(s, 1);
      s += __shfl_xor(s, 2);
      s += __shfl_xor(s, 4);
      s += __shfl_xor(s, 8);
      const float sc = MASSF / s;
#pragma unroll
      for (int j = 0; j < 16; ++j) p[i][j] *= sc;
    }
  };
  auto colpass = [&]() {
    float tmp[16];
#pragma unroll
    for (int j = 0; j < 16; ++j) tmp[j] = ((p[0][j] + p[1][j]) + (p[2][j] + p[3][j]));
#pragma unroll
    for (int j = 0; j < 16; ++j) {
      tmp[j] += __shfl_xor(tmp[j], 16);
      tmp[j] += __shfl_xor(tmp[j], 32);
    }
    if (l < 16) {
#pragma unroll
      for (int q = 0; q < 4; ++q)
        *(f32x4*)&red[wv][l * 16 + q * 4] = *(const f32x4*)&tmp[q * 4];
    }
    __syncthreads();
    if (t < 256) {
      float s = red[0][t];
#pragma unroll
      for (int w = 1; w < 16; ++w) s += red[w][t];
      scal[t] = MASSF / s;
    }
    __syncthreads();
#pragma unroll
    for (int j = 0; j < 16; ++j) {
      const float sc = scal[tc * 16 + j];
#pragma unroll
      for (int i = 0; i < 4; ++i) p[i][j] *= sc;
    }
    __syncthreads();
  };
  for (int it = 0; it < 7; ++it) {
    rowpass();
    colpass();
  }
  rowpass();
#pragma unroll
  for (int i = 0; i < 4; ++i)
#pragma unroll
    for (int q = 0; q < 4; ++q)
      *(f32x4*)&Pg[(size_t)(trw * 4 + i) * NM + tc * 16 + q * 4] = *(const f32x4*)&p[i][q * 4];
}

extern "C" void kernel_launch(void* const* d_in, const int* in_sizes, int n_in, void* d_out,
                              int out_size, void* d_ws, size_t ws_size, hipStream_t stream) {
  const float* tra_x = (const float*)d_in[0];
  const float* det_x = (const float*)d_in[1];
  const float* W_enc = (const float*)d_in[2];
  const float* b_enc = (const float*)d_in[3];
  const float* W1 = (const float*)d_in[4];
  const float* b1 = (const float*)d_in[5];
  const float* W2 = (const float*)d_in[6];
  const float* b2 = (const float*)d_in[7];
  const float* eps = (const float*)d_in[8];
  float* out = (float*)d_out;

  const size_t SZ = (size_t)NR * ND;
  float* h = (float*)d_ws;
  short* hbf = (short*)(h + SZ);
  short* baseb = hbf + SZ;
  short* n1b = baseb + SZ;
  short* featT = n1b + SZ;
  short* featD = featT + SZ;
  float* sq = (float*)(featD + SZ);
  float* nT = sq + NR;
  float* nD = nT + NR;
  int* idx = (int*)(nD + NR);
  short* w2t = (short*)(idx + (size_t)NR * NK);
  short* w1cat = w2t + 256 * 256;
  float* biascat = (float*)(w1cat + 512 * 256);
  float* S = out;  // gram scratch lives in d_out until cost overwrites it

  const float* xs[2] = {tra_x, det_x};
  short* feats[2] = {featT, featD};
  float* nrms[2] = {nT, nD};

  prep_k<<<768, 256, 0, stream>>>(W1, b1, W2, w2t, w1cat, biascat);
  for (int s2 = 0; s2 < 2; ++s2) {
    gemm_nn2_k<<<dim3(2, 256), 256, 0, stream>>>(xs[s2], W_enc, b_enc, h, hbf);
    mlp1_mfma_k<<<dim3(4, 256), 256, 0, stream>>>(hbf, w1cat, biascat, baseb, n1b);
    gemm_nt2_k<<<dim3(2, 4, NG), 256, 0, stream>>>(h, S);
    diag_k<<<NG, 256, 0, stream>>>(S, sq);
    topk_k<<<4096, 256, 0, stream>>>(S, sq, idx);
    edgemlp_mfma6_k<<<NR / NB, 512, 0, stream>>>(baseb, n1b, idx, w2t, b2, feats[s2]);
    normrow_bf_k<<<4096, 256, 0, stream>>>(feats[s2], nrms[s2]);
  }
  cost_mfma_k<<<dim3(2, 4, NG), 256, 0, stream>>>(featT, featD, nT, nD, eps, out);
  sinkhorn_k<<<NG, 1024, 0, stream>>>(out);
}